// Round 1
// 6098.750 us; speedup vs baseline: 1.8587x; 1.8587x over previous
//
#include <hip/hip_runtime.h>

typedef unsigned short ushort_t;
typedef unsigned int uint32;
typedef unsigned long long uint64;
typedef __attribute__((ext_vector_type(8))) __bf16 bf16x8;
typedef __attribute__((ext_vector_type(4))) float f32x4;

#define BB 64
#define LL 1024
#define DD 64
#define HH 512
#define HSEQ_N (BB * LL * HH)
#define HN_OFF HSEQ_N
#define XH_OFF (HSEQ_N + BB * HH)

#define NGRP 4          // batch groups (16 rows each)
#define NCOL 16         // column groups (32 cols each)
// d_ws layout: [0,1024) counters (one uint32 per group, 256B apart)
//              [1024, 1024+131072) h exchange: [par][g][16 rows][512] bf16
//              [132096, +32768) LN partials: [par][g][c][T*16+row] float2
#define WS_CNT_STRIDE 64
#define WS_HEX_OFF 1024
#define WS_PS_OFF (1024 + 2 * NGRP * 16 * 512 * 2)

__device__ __forceinline__ ushort_t f2bf(float f) {
  union { float f; uint32 i; } v; v.f = f;
  uint32 r = (v.i + 0x7fffu + ((v.i >> 16) & 1u)) >> 16;
  return (ushort_t)r;
}
__device__ __forceinline__ __bf16 u2b(ushort_t u) {
  union { ushort_t u; __bf16 b; } v; v.u = u; return v.b;
}
__device__ __forceinline__ bf16x8 cvt8(const float* p) {
  float4 a = *(const float4*)p;
  float4 b = *(const float4*)(p + 4);
  bf16x8 r;
  r[0] = u2b(f2bf(a.x)); r[1] = u2b(f2bf(a.y)); r[2] = u2b(f2bf(a.z)); r[3] = u2b(f2bf(a.w));
  r[4] = u2b(f2bf(b.x)); r[5] = u2b(f2bf(b.y)); r[6] = u2b(f2bf(b.z)); r[7] = u2b(f2bf(b.w));
  return r;
}
__device__ __forceinline__ float sigm(float x) { return 1.0f / (1.0f + __expf(-x)); }
__device__ __forceinline__ float tanh_f(float x) {
  x = fminf(20.f, fmaxf(-20.f, x));
  float e = __expf(2.0f * x);
  return (e - 1.0f) / (e + 1.0f);
}

// Point-coherent exchange primitives: relaxed agent-scope atomics compile to
// sc1 write-through stores / L2-bypass loads. Data is at the coherence point
// (Infinity Cache) once vmcnt drains (which __syncthreads already does), so
// NO release fence (buffer_wbl2) and NO __threadfence (buffer_inv) is needed.
__device__ __forceinline__ void st_u32_agent(uint32* p, uint32 v) {
  __hip_atomic_store(p, v, __ATOMIC_RELAXED, __HIP_MEMORY_SCOPE_AGENT);
}
__device__ __forceinline__ void st_u64_agent(uint64* p, uint64 v) {
  __hip_atomic_store(p, v, __ATOMIC_RELAXED, __HIP_MEMORY_SCOPE_AGENT);
}
__device__ __forceinline__ uint64 ld_u64_agent(const uint64* p) {
  return __hip_atomic_load((uint64*)p, __ATOMIC_RELAXED, __HIP_MEMORY_SCOPE_AGENT);
}

// 64 blocks = 4 batch-groups x 16 col-groups. 384 threads = 6 waves; wave v
// owns gate s=v>>1 (r,z,n), col-subtile T=v&1 (16 cols). W_hh/W_ih fragments
// for the wave's 16 output rows live in 72 VGPRs for the whole kernel.
// Per-step inter-block h exchange via d_ws + monotonic per-group counter.
__global__ __launch_bounds__(384) void gru_kernel(
    const float* __restrict__ x, const float* __restrict__ h0,
    const float* __restrict__ Wih, const float* __restrict__ Whh,
    const float* __restrict__ bih, const float* __restrict__ bhh,
    const float* __restrict__ gamma, const float* __restrict__ beta,
    float* __restrict__ out, uint32* __restrict__ cnt,
    ushort_t* __restrict__ h_ex, float2* __restrict__ ps_ex)
{
  __shared__ __align__(16) ushort_t Abuf[16 * 520];   // h_{t-1} bf16 (full 512 cols)
  __shared__ __align__(16) ushort_t xbuf[16 * 80];    // x_t bf16
  __shared__ float grz[4][16 * 17];                   // sigmoid(r/z) tiles [s*2+T]
  __shared__ float2 statb[16];                        // (mu, rstd) per batch row

  const int tid = threadIdx.x;
  const int v = tid >> 6, lane = tid & 63, lo = lane & 15, hi = lane >> 4;
  const int s = v >> 1, T = v & 1;
  const int g = blockIdx.x & 3, c = blockIdx.x >> 2;  // same-g blocks 2 XCDs apart
  const int b0 = g * 16;
  const int colj = c * 32 + T * 16 + lo;              // h-index this lane produces
  const int rowW = s * HH + colj;                      // W row (gate-major 3H layout)

  // ---- weights into registers (bf16 fragments) ----
  bf16x8 wB[16], wI[2];
  {
    const float* wr = Whh + (size_t)rowW * HH + hi * 8;
    #pragma unroll
    for (int ks = 0; ks < 16; ++ks) wB[ks] = cvt8(wr + ks * 32);
    const float* wir = Wih + (size_t)rowW * DD + hi * 8;
    #pragma unroll
    for (int ks = 0; ks < 2; ++ks) wI[ks] = cvt8(wir + ks * 32);
  }
  const float bsum = bih[rowW] + bhh[rowW];  // r/z combined bias
  const float bgh = bhh[rowW];               // n: hidden-side bias
  const float bgi = bih[rowW];               // n: input-side bias

  float hprev[4], gmv = 0.f, btv = 0.f;
  if (s == 2) {
    gmv = gamma[colj]; btv = beta[colj];
    #pragma unroll
    for (int i = 0; i < 4; ++i) hprev[i] = h0[(size_t)(b0 + hi * 4 + i) * HH + colj];
  }

  // ---- stage h0 -> Abuf, x(0) -> xbuf ----
  for (int i = tid; i < 16 * 512; i += 384) {
    int row = i >> 9, col = i & 511;
    Abuf[row * 520 + col] = f2bf(h0[(size_t)(b0 + row) * HH + col]);
  }
  for (int i = tid; i < 1024; i += 384) {
    int row = i >> 6, d = i & 63;
    xbuf[row * 80 + d] = f2bf(x[((size_t)(b0 + row) * LL + 0) * DD + d]);
  }
  __syncthreads();

  uint32* mycnt = cnt + g * WS_CNT_STRIDE;

  for (int t = 0; t < LL; ++t) {
    // prefetch x(t+1) into regs (overlaps MFMA phase)
    float xr[3];
    {
      int t1 = (t + 1 < LL) ? (t + 1) : (LL - 1);
      int n = 0;
      for (int i = tid; i < 1024; i += 384, ++n)
        xr[n] = x[((size_t)(b0 + (i >> 6)) * LL + t1) * DD + (i & 63)];
    }

    // ---- MFMA phase: A from LDS, B from registers ----
    f32x4 a0, a1, agi;
    #pragma unroll
    for (int i = 0; i < 4; ++i) {
      a0[i] = (s < 2) ? bsum : bgh;
      a1[i] = 0.f;
      agi[i] = bgi;
    }
    #pragma unroll
    for (int ks = 0; ks < 2; ++ks) {
      bf16x8 av = *(const bf16x8*)&xbuf[lo * 80 + ks * 32 + hi * 8];
      if (s < 2) a0 = __builtin_amdgcn_mfma_f32_16x16x32_bf16(av, wI[ks], a0, 0, 0, 0);
      else       agi = __builtin_amdgcn_mfma_f32_16x16x32_bf16(av, wI[ks], agi, 0, 0, 0);
    }
    #pragma unroll
    for (int ks = 0; ks < 16; ++ks) {
      bf16x8 av = *(const bf16x8*)&Abuf[lo * 520 + ks * 32 + hi * 8];
      if (ks & 1) a1 = __builtin_amdgcn_mfma_f32_16x16x32_bf16(av, wB[ks], a1, 0, 0, 0);
      else        a0 = __builtin_amdgcn_mfma_f32_16x16x32_bf16(av, wB[ks], a0, 0, 0, 0);
    }
    f32x4 gacc;
    #pragma unroll
    for (int i = 0; i < 4; ++i) gacc[i] = a0[i] + a1[i];

    if (s < 2) {
      #pragma unroll
      for (int i = 0; i < 4; ++i) grz[s * 2 + T][(hi * 4 + i) * 17 + lo] = sigm(gacc[i]);
    }
    __syncthreads();  // C: r,z tiles visible

    if (s == 2) {
      float hn[4];
      #pragma unroll
      for (int i = 0; i < 4; ++i) {
        float r = grz[T][(hi * 4 + i) * 17 + lo];
        float z = grz[2 + T][(hi * 4 + i) * 17 + lo];
        float n = tanh_f(agi[i] + r * gacc[i]);
        hn[i] = z * (hprev[i] - n) + n;
      }
      // pack 2 adjacent cols (even/odd lane pair) into one u32 -> agent store
      uint32* hx32 = (uint32*)(h_ex + (size_t)(((t & 1) * NGRP + g) * 16) * 512);
      {
        uint32 pk[4];
        #pragma unroll
        for (int i = 0; i < 4; ++i) {
          uint32 m = (uint32)f2bf(hn[i]);
          uint32 o = (uint32)__shfl_xor((int)m, 1, 64);
          pk[i] = (lo & 1) ? ((o & 0xffffu) | (m << 16)) : (m | (o << 16));
        }
        int p = lo & 1;
        int cb = c * 16 + T * 8 + (lo >> 1);
        st_u32_agent(&hx32[(hi * 4 + 2 * p) * 256 + cb], pk[2 * p]);
        st_u32_agent(&hx32[(hi * 4 + 2 * p + 1) * 256 + cb], pk[2 * p + 1]);
      }
      // LN partials over this wave's 16 cols
      #pragma unroll
      for (int i = 0; i < 4; ++i) {
        float sv = hn[i], sq = hn[i] * hn[i];
        #pragma unroll
        for (int m = 1; m < 16; m <<= 1) {
          sv += __shfl_xor(sv, m, 64);
          sq += __shfl_xor(sq, m, 64);
        }
        if (lo == 0) {
          float2* pp = ps_ex + (size_t)(((t & 1) * NGRP + g) * NCOL + c) * 32 + T * 16;
          union { float2 f; uint64 u; } uu; uu.f = make_float2(sv, sq);
          st_u64_agent((uint64*)&pp[hi * 4 + i], uu.u);
        }
      }
      if (t == LL - 1) {
        #pragma unroll
        for (int i = 0; i < 4; ++i)
          out[(size_t)HN_OFF + (size_t)(b0 + hi * 4 + i) * HH + colj] = hn[i];
      }
      #pragma unroll
      for (int i = 0; i < 4; ++i) hprev[i] = hn[i];
    }
    __syncthreads();  // D: vmcnt(0) drain -> all agent stores are at the IC

    if (tid == 0) {
      __hip_atomic_fetch_add(mycnt, 1u, __ATOMIC_RELAXED, __HIP_MEMORY_SCOPE_AGENT);
      uint32 tgt = (uint32)NCOL * (uint32)(t + 1);
      while (__hip_atomic_load(mycnt, __ATOMIC_RELAXED, __HIP_MEMORY_SCOPE_AGENT) < tgt)
        __builtin_amdgcn_s_sleep(1);
    }
    __syncthreads();  // E: whole block past the sync point (no fence needed)

    // ---- stage full h_t -> Abuf (16 KB) via agent loads, x(t+1) -> xbuf ----
    {
      const uint64* hx8 = (const uint64*)(h_ex + (size_t)(((t & 1) * NGRP + g) * 16) * 512);
      for (int i = tid; i < 2048; i += 384) {
        uint64 vv = ld_u64_agent(hx8 + i);
        int row = i >> 7, c8 = i & 127;
        *(uint64*)&Abuf[row * 520 + c8 * 4] = vv;
      }
      int n = 0;
      for (int i = tid; i < 1024; i += 384, ++n)
        xbuf[(i >> 6) * 80 + (i & 63)] = f2bf(xr[n]);
    }
    // wave 3: fold the 32 per-block LN partials into (mu, rstd) per row
    if (v == 3) {
      int r = lane >> 2, q = lane & 3;
      const float2* pp = ps_ex + (size_t)(((t & 1) * NGRP + g) * NCOL) * 32;
      float sv = 0.f, sq = 0.f;
      #pragma unroll
      for (int j = 0; j < 8; ++j) {
        int u = q * 8 + j;                       // u = c*2+T combo
        union { uint64 u64; float2 f; } uu;
        uu.u64 = ld_u64_agent((const uint64*)&pp[(u >> 1) * 32 + (u & 1) * 16 + r]);
        sv += uu.f.x; sq += uu.f.y;
      }
      sv += __shfl_xor(sv, 1, 64); sq += __shfl_xor(sq, 1, 64);
      sv += __shfl_xor(sv, 2, 64); sq += __shfl_xor(sq, 2, 64);
      if (q == 0) {
        float mu = sv * (1.0f / 512.0f);
        float var = sq * (1.0f / 512.0f) - mu * mu;
        statb[r] = make_float2(mu, rsqrtf(var + 1e-5f));
      }
    }
    __syncthreads();  // F: Abuf/xbuf/stats ready

    if (s == 2) {     // hseq(t) write overlaps next step's MFMA phase
      #pragma unroll
      for (int i = 0; i < 4; ++i) {
        float2 st = statb[hi * 4 + i];
        float y = (hprev[i] - st.x) * st.y * gmv + btv;
        out[((size_t)(b0 + hi * 4 + i) * LL + t) * HH + colj] = y;
      }
    }
  }
}

// x_hat = h_seq @ W_pred^T + b_pred (reads h_seq from out region, fp32).
__global__ __launch_bounds__(256) void pred_kernel(
    float* __restrict__ out, const float* __restrict__ Wp, const float* __restrict__ bp)
{
  __shared__ uint32 WL[64 * 256];  // [k2][(d+k2)&63] = bf16x2 of W[d][2k2..]
  __shared__ uint32 hb[4 * 256];
  const int tid = threadIdx.x;
  const int d = tid & 63;
  const int rg = tid >> 6;

  for (int idx = tid; idx < 64 * 256; idx += 256) {
    int dd = idx >> 8, k2 = idx & 255;
    float2 w2 = *(const float2*)&Wp[(size_t)dd * HH + k2 * 2];
    WL[k2 * 64 + ((dd + k2) & 63)] = (uint32)f2bf(w2.x) | ((uint32)f2bf(w2.y) << 16);
  }
  float bpf = bp[d];
  __syncthreads();

  const int R0 = blockIdx.x * 64;
  for (int c = 0; c < 16; ++c) {
    #pragma unroll
    for (int ii = 0; ii < 4; ++ii) {
      int idx = ii * 256 + tid;
      int r = idx >> 8, k2 = idx & 255;
      float2 h2 = *(const float2*)&out[(size_t)(R0 + c * 4 + r) * HH + k2 * 2];
      hb[r * 256 + k2] = (uint32)f2bf(h2.x) | ((uint32)f2bf(h2.y) << 16);
    }
    __syncthreads();
    float acc = 0.f;
    #pragma unroll 8
    for (int k2 = 0; k2 < 256; ++k2) {
      uint32 wv = WL[k2 * 64 + ((d + k2) & 63)];
      uint32 hv = hb[rg * 256 + k2];
      union { uint32 i; float f; } a0, a1, c0, c1;
      a0.i = wv << 16; a1.i = wv & 0xffff0000u;
      c0.i = hv << 16; c1.i = hv & 0xffff0000u;
      acc += a0.f * c0.f + a1.f * c1.f;
    }
    out[(size_t)XH_OFF + (size_t)(R0 + c * 4 + rg) * DD + d] = acc + bpf;
    __syncthreads();
  }
}

extern "C" void kernel_launch(void* const* d_in, const int* in_sizes, int n_in,
                              void* d_out, int out_size, void* d_ws, size_t ws_size,
                              hipStream_t stream) {
  const float* x   = (const float*)d_in[0];
  const float* h0  = (const float*)d_in[1];
  const float* Wih = (const float*)d_in[2];
  const float* Whh = (const float*)d_in[3];
  const float* bih = (const float*)d_in[4];
  const float* bhh = (const float*)d_in[5];
  const float* gam = (const float*)d_in[6];
  const float* bet = (const float*)d_in[7];
  const float* Wp  = (const float*)d_in[8];
  const float* bp  = (const float*)d_in[9];
  float* out = (float*)d_out;

  uint32* cnt    = (uint32*)d_ws;
  ushort_t* h_ex = (ushort_t*)((char*)d_ws + WS_HEX_OFF);
  float2* ps_ex  = (float2*)((char*)d_ws + WS_PS_OFF);

  // counters must start at 0 every launch (harness poisons d_ws with 0xAA)
  hipMemsetAsync(d_ws, 0, 1024, stream);

  hipLaunchKernelGGL(gru_kernel, dim3(NGRP * NCOL), dim3(384), 0, stream,
                     x, h0, Wih, Whh, bih, bhh, gam, bet, out, cnt, h_ex, ps_ex);
  hipLaunchKernelGGL(pred_kernel, dim3(1024), dim3(256), 0, stream,
                     out, Wp, bp);
}

// Round 2
// 4836.165 us; speedup vs baseline: 2.3439x; 1.2611x over previous
//
#include <hip/hip_runtime.h>

typedef unsigned short ushort_t;
typedef unsigned int uint32;
typedef unsigned long long uint64;
typedef __attribute__((ext_vector_type(8))) __bf16 bf16x8;
typedef __attribute__((ext_vector_type(4))) float f32x4;

#define BB 64
#define LL 1024
#define DD 64
#define HH 512
#define HSEQ_N (BB * LL * HH)
#define HN_OFF HSEQ_N
#define XH_OFF (HSEQ_N + BB * HH)

#define NGRP 4          // batch groups (16 rows each)
#define NBLK 8          // blocks per group (64 cols x 3 gates each)
#define NT 4            // col-subtiles of 16 per block
// d_ws layout: [0,1024) flags: group g flag c at (g*64 + c*8) u32 (32B apart)
//              [1024, 1024+131072) h exchange: [par][g][16 rows][512] bf16
//              [132096, +32768) LN partials: [par][g][c*4+T][row] float2
#define WS_HEX_OFF 1024
#define WS_PS_OFF (1024 + 2 * NGRP * 16 * 512 * 2)

__device__ __forceinline__ ushort_t f2bf(float f) {
  union { float f; uint32 i; } v; v.f = f;
  uint32 r = (v.i + 0x7fffu + ((v.i >> 16) & 1u)) >> 16;
  return (ushort_t)r;
}
__device__ __forceinline__ __bf16 u2b(ushort_t u) {
  union { ushort_t u; __bf16 b; } v; v.u = u; return v.b;
}
__device__ __forceinline__ bf16x8 cvt8(const float* p) {
  float4 a = *(const float4*)p;
  float4 b = *(const float4*)(p + 4);
  bf16x8 r;
  r[0] = u2b(f2bf(a.x)); r[1] = u2b(f2bf(a.y)); r[2] = u2b(f2bf(a.z)); r[3] = u2b(f2bf(a.w));
  r[4] = u2b(f2bf(b.x)); r[5] = u2b(f2bf(b.y)); r[6] = u2b(f2bf(b.z)); r[7] = u2b(f2bf(b.w));
  return r;
}
__device__ __forceinline__ float sigm(float x) { return 1.0f / (1.0f + __expf(-x)); }
__device__ __forceinline__ float tanh_f(float x) {
  x = fminf(20.f, fmaxf(-20.f, x));
  float e = __expf(2.0f * x);
  return (e - 1.0f) / (e + 1.0f);
}

// Point-coherent exchange: relaxed agent-scope atomics (sc-bit write-through
// stores / cache-bypass loads). Ordering comes from the vmcnt(0) drain inside
// __syncthreads: data is at the coherence point before the flag store issues.
__device__ __forceinline__ void st_u32_agent(uint32* p, uint32 v) {
  __hip_atomic_store(p, v, __ATOMIC_RELAXED, __HIP_MEMORY_SCOPE_AGENT);
}
__device__ __forceinline__ void st_u64_agent(uint64* p, uint64 v) {
  __hip_atomic_store(p, v, __ATOMIC_RELAXED, __HIP_MEMORY_SCOPE_AGENT);
}
__device__ __forceinline__ uint64 ld_u64_agent(const uint64* p) {
  return __hip_atomic_load((uint64*)p, __ATOMIC_RELAXED, __HIP_MEMORY_SCOPE_AGENT);
}

// 32 blocks = 4 batch-groups x 8 col-groups, 768 threads = 12 waves.
// Wave v: gate s=v>>2 (r,z,n), col-subtile T=v&3 (16 cols of the block's 64).
// Weights for the wave's 16 output rows live in 72 VGPRs for the whole kernel.
// Per-step sync: distributed per-block flags (no serialized central atomic).
__global__ __launch_bounds__(768) void gru_kernel(
    const float* __restrict__ x, const float* __restrict__ h0,
    const float* __restrict__ Wih, const float* __restrict__ Whh,
    const float* __restrict__ bih, const float* __restrict__ bhh,
    const float* __restrict__ gamma, const float* __restrict__ beta,
    float* __restrict__ out, uint32* __restrict__ cnt,
    ushort_t* __restrict__ h_ex, float2* __restrict__ ps_ex)
{
  __shared__ __align__(16) ushort_t Abuf[16 * 520];   // h_{t-1} bf16 (full 512 cols)
  __shared__ __align__(16) ushort_t xbuf[16 * 80];    // x_t bf16
  __shared__ float grz[8][16 * 17];                   // sigmoid(r/z) tiles [s*4+T]
  __shared__ float2 statb[16];                        // (mu, rstd) per batch row

  const int tid = threadIdx.x;
  const int v = tid >> 6, lane = tid & 63, lo = lane & 15, hi = lane >> 4;
  const int s = v >> 2, T = v & 3;
  const int g = blockIdx.x & 3, c = blockIdx.x >> 2;  // c in [0,8)
  const int b0 = g * 16;
  const int colj = c * 64 + T * 16 + lo;              // h-index this lane produces
  const int rowW = s * HH + colj;                      // W row (gate-major 3H layout)

  // ---- weights into registers (bf16 fragments) ----
  bf16x8 wB[16], wI[2];
  {
    const float* wr = Whh + (size_t)rowW * HH + hi * 8;
    #pragma unroll
    for (int ks = 0; ks < 16; ++ks) wB[ks] = cvt8(wr + ks * 32);
    const float* wir = Wih + (size_t)rowW * DD + hi * 8;
    #pragma unroll
    for (int ks = 0; ks < 2; ++ks) wI[ks] = cvt8(wir + ks * 32);
  }
  const float bsum = bih[rowW] + bhh[rowW];  // r/z combined bias
  const float bgh = bhh[rowW];               // n: hidden-side bias
  const float bgi = bih[rowW];               // n: input-side bias

  float hprev[4], gmv = 0.f, btv = 0.f;
  if (s == 2) {
    gmv = gamma[colj]; btv = beta[colj];
    #pragma unroll
    for (int i = 0; i < 4; ++i) hprev[i] = h0[(size_t)(b0 + hi * 4 + i) * HH + colj];
  }

  // ---- stage h0 -> Abuf, x(0) -> xbuf ----
  for (int i = tid; i < 16 * 512; i += 768) {
    int row = i >> 9, col = i & 511;
    Abuf[row * 520 + col] = f2bf(h0[(size_t)(b0 + row) * HH + col]);
  }
  for (int i = tid; i < 1024; i += 768) {
    int row = i >> 6, d = i & 63;
    xbuf[row * 80 + d] = f2bf(x[((size_t)(b0 + row) * LL + 0) * DD + d]);
  }
  __syncthreads();

  uint32* fb = cnt + g * 64;   // 8 flags, 32B apart, per group

  for (int t = 0; t < LL; ++t) {
    // prefetch x(t+1) into regs (waves 1..11; wave 0 will be polling)
    float xr[2];
    if (v > 0) {
      int t1 = (t + 1 < LL) ? (t + 1) : (LL - 1);
      int n = 0;
      for (int i = tid - 64; i < 1024; i += 704, ++n)
        xr[n] = x[((size_t)(b0 + (i >> 6)) * LL + t1) * DD + (i & 63)];
    }

    // ---- MFMA phase: A from LDS, B from registers ----
    f32x4 a0, a1, agi;
    #pragma unroll
    for (int i = 0; i < 4; ++i) {
      a0[i] = (s < 2) ? bsum : bgh;
      a1[i] = 0.f;
      agi[i] = bgi;
    }
    #pragma unroll
    for (int ks = 0; ks < 2; ++ks) {
      bf16x8 av = *(const bf16x8*)&xbuf[lo * 80 + ks * 32 + hi * 8];
      if (s < 2) a0 = __builtin_amdgcn_mfma_f32_16x16x32_bf16(av, wI[ks], a0, 0, 0, 0);
      else       agi = __builtin_amdgcn_mfma_f32_16x16x32_bf16(av, wI[ks], agi, 0, 0, 0);
    }
    #pragma unroll
    for (int ks = 0; ks < 16; ++ks) {
      bf16x8 av = *(const bf16x8*)&Abuf[lo * 520 + ks * 32 + hi * 8];
      if (ks & 1) a1 = __builtin_amdgcn_mfma_f32_16x16x32_bf16(av, wB[ks], a1, 0, 0, 0);
      else        a0 = __builtin_amdgcn_mfma_f32_16x16x32_bf16(av, wB[ks], a0, 0, 0, 0);
    }
    f32x4 gacc;
    #pragma unroll
    for (int i = 0; i < 4; ++i) gacc[i] = a0[i] + a1[i];

    if (s < 2) {
      #pragma unroll
      for (int i = 0; i < 4; ++i) grz[s * 4 + T][(hi * 4 + i) * 17 + lo] = sigm(gacc[i]);
    }
    __syncthreads();  // C: r,z tiles visible

    if (s == 2) {
      float hn[4];
      #pragma unroll
      for (int i = 0; i < 4; ++i) {
        float r = grz[T][(hi * 4 + i) * 17 + lo];
        float z = grz[4 + T][(hi * 4 + i) * 17 + lo];
        float n = tanh_f(agi[i] + r * gacc[i]);
        hn[i] = z * (hprev[i] - n) + n;
      }
      // pack 2 adjacent cols (even/odd lane pair) into one u32 -> agent store
      uint32* hx32 = (uint32*)(h_ex + (size_t)(((t & 1) * NGRP + g) * 16) * 512);
      {
        uint32 pk[4];
        #pragma unroll
        for (int i = 0; i < 4; ++i) {
          uint32 m = (uint32)f2bf(hn[i]);
          uint32 o = (uint32)__shfl_xor((int)m, 1, 64);
          pk[i] = (lo & 1) ? ((o & 0xffffu) | (m << 16)) : (m | (o << 16));
        }
        int p = lo & 1;
        int cb = c * 32 + T * 8 + (lo >> 1);
        st_u32_agent(&hx32[(hi * 4 + 2 * p) * 256 + cb], pk[2 * p]);
        st_u32_agent(&hx32[(hi * 4 + 2 * p + 1) * 256 + cb], pk[2 * p + 1]);
      }
      // LN partials over this wave's 16 cols
      #pragma unroll
      for (int i = 0; i < 4; ++i) {
        float sv = hn[i], sq = hn[i] * hn[i];
        #pragma unroll
        for (int m = 1; m < 16; m <<= 1) {
          sv += __shfl_xor(sv, m, 64);
          sq += __shfl_xor(sq, m, 64);
        }
        if (lo == 0) {
          float2* pp = ps_ex + ((size_t)((t & 1) * NGRP + g) * 32 + (c * 4 + T)) * 16;
          union { float2 f; uint64 u; } uu; uu.f = make_float2(sv, sq);
          st_u64_agent((uint64*)&pp[hi * 4 + i], uu.u);
        }
      }
      if (t == LL - 1) {
        #pragma unroll
        for (int i = 0; i < 4; ++i)
          out[(size_t)HN_OFF + (size_t)(b0 + hi * 4 + i) * HH + colj] = hn[i];
      }
      #pragma unroll
      for (int i = 0; i < 4; ++i) hprev[i] = hn[i];
    }
    __syncthreads();  // D: vmcnt(0) drain -> all agent stores are at the IC

    // signal own flag (ordered after D's drain), fill xbuf while wave 0 polls
    if (tid == 0) st_u32_agent(&fb[c * 8], (uint32)(t + 1));
    if (v > 0) {
      int n = 0;
      for (int i = tid - 64; i < 1024; i += 704, ++n)
        xbuf[(i >> 6) * 80 + (i & 63)] = f2bf(xr[n]);
    }
    if (v == 0) {
      const uint32 tgt = (uint32)(t + 1);
      while (true) {
        uint32 f = (lane < 8)
          ? __hip_atomic_load(&fb[lane * 8], __ATOMIC_RELAXED, __HIP_MEMORY_SCOPE_AGENT)
          : tgt;
        if (__all((int)(f >= tgt))) break;
        __builtin_amdgcn_s_sleep(1);
      }
    }
    __syncthreads();  // E: all 8 writers' data visible

    // ---- stage full h_t -> Abuf (16 KB) via agent loads; wave 3 folds LN ----
    if (v != 3) {
      const uint64* hx8 = (const uint64*)(h_ex + (size_t)(((t & 1) * NGRP + g) * 16) * 512);
      int sid = (v < 3) ? tid : tid - 64;   // 704 staging threads
      for (int i = sid; i < 2048; i += 704) {
        uint64 vv = ld_u64_agent(hx8 + i);
        int row = i >> 7, c8 = i & 127;
        *(uint64*)&Abuf[row * 520 + c8 * 4] = vv;
      }
    } else {
      // fold the 32 per-group LN partials into (mu, rstd) per row
      int r = lane >> 2, q = lane & 3;
      const float2* pp = ps_ex + (size_t)((t & 1) * NGRP + g) * 32 * 16;
      float sv = 0.f, sq = 0.f;
      #pragma unroll
      for (int j = 0; j < 8; ++j) {
        int u = q * 8 + j;                   // u = c*4+T combo
        union { uint64 u64; float2 f; } uu;
        uu.u64 = ld_u64_agent((const uint64*)&pp[u * 16 + r]);
        sv += uu.f.x; sq += uu.f.y;
      }
      sv += __shfl_xor(sv, 1, 64); sq += __shfl_xor(sq, 1, 64);
      sv += __shfl_xor(sv, 2, 64); sq += __shfl_xor(sq, 2, 64);
      if (q == 0) {
        float mu = sv * (1.0f / 512.0f);
        float var = sq * (1.0f / 512.0f) - mu * mu;
        statb[r] = make_float2(mu, rsqrtf(var + 1e-5f));
      }
    }
    __syncthreads();  // F: Abuf/xbuf/stats ready

    if (s == 2) {     // hseq(t) write overlaps next step's MFMA phase
      #pragma unroll
      for (int i = 0; i < 4; ++i) {
        float2 st = statb[hi * 4 + i];
        float y = (hprev[i] - st.x) * st.y * gmv + btv;
        out[((size_t)(b0 + hi * 4 + i) * LL + t) * HH + colj] = y;
      }
    }
  }
}

// x_hat = h_seq @ W_pred^T + b_pred, MFMA-based. Wave v owns output cols
// d = v*16 + lo (N=64 = 4 waves x 16). A-fragments straight from global
// (16 rows x 128B coalesced segments); W_pred in registers; fp32 accum.
__global__ __launch_bounds__(256) void pred_kernel(
    float* __restrict__ out, const float* __restrict__ Wp, const float* __restrict__ bp)
{
  const int tid = threadIdx.x;
  const int v = tid >> 6, lane = tid & 63, lo = lane & 15, hi = lane >> 4;
  const int d = v * 16 + lo;

  bf16x8 wP[16];
  const float* wr = Wp + (size_t)d * HH + hi * 8;
  #pragma unroll
  for (int ks = 0; ks < 16; ++ks) wP[ks] = cvt8(wr + ks * 32);
  const float bpf = bp[d];

  #pragma unroll
  for (int rt = 0; rt < 2; ++rt) {
    const size_t row0 = ((size_t)blockIdx.x * 2 + rt) * 16;
    const float* ap = out + (row0 + lo) * HH + hi * 8;
    f32x4 acc;
    #pragma unroll
    for (int i = 0; i < 4; ++i) acc[i] = 0.f;
    #pragma unroll
    for (int ks = 0; ks < 16; ++ks) {
      bf16x8 av = cvt8(ap + ks * 32);
      acc = __builtin_amdgcn_mfma_f32_16x16x32_bf16(av, wP[ks], acc, 0, 0, 0);
    }
    #pragma unroll
    for (int i = 0; i < 4; ++i)
      out[(size_t)XH_OFF + (row0 + hi * 4 + i) * DD + d] = acc[i] + bpf;
  }
}

extern "C" void kernel_launch(void* const* d_in, const int* in_sizes, int n_in,
                              void* d_out, int out_size, void* d_ws, size_t ws_size,
                              hipStream_t stream) {
  const float* x   = (const float*)d_in[0];
  const float* h0  = (const float*)d_in[1];
  const float* Wih = (const float*)d_in[2];
  const float* Whh = (const float*)d_in[3];
  const float* bih = (const float*)d_in[4];
  const float* bhh = (const float*)d_in[5];
  const float* gam = (const float*)d_in[6];
  const float* bet = (const float*)d_in[7];
  const float* Wp  = (const float*)d_in[8];
  const float* bp  = (const float*)d_in[9];
  float* out = (float*)d_out;

  uint32* cnt    = (uint32*)d_ws;
  ushort_t* h_ex = (ushort_t*)((char*)d_ws + WS_HEX_OFF);
  float2* ps_ex  = (float2*)((char*)d_ws + WS_PS_OFF);

  // flags must start at 0 every launch (harness poisons d_ws with 0xAA)
  hipMemsetAsync(d_ws, 0, 1024, stream);

  hipLaunchKernelGGL(gru_kernel, dim3(NGRP * NBLK), dim3(768), 0, stream,
                     x, h0, Wih, Whh, bih, bhh, gam, bet, out, cnt, h_ex, ps_ex);
  hipLaunchKernelGGL(pred_kernel, dim3(BB * LL / 32), dim3(256), 0, stream,
                     out, Wp, bp);
}